// Round 3
// baseline (417.164 us; speedup 1.0000x reference)
//
#include <hip/hip_runtime.h>
#include <math.h>

#define N_TOK   16384
#define D_MODEL 4096
#define N_EXP   16
#define N_SEL   4
#define WELEM   (N_EXP * D_MODEL)   // 65536 per weight matrix
#define TILES   2                   // token tiles per block (32 tokens)

typedef __bf16 bf16x8 __attribute__((ext_vector_type(8)));
typedef float  f32x4  __attribute__((ext_vector_type(4)));

#define MFMA(a, b, c) __builtin_amdgcn_mfma_f32_16x16x32_bf16((a), (b), (c), 0, 0, 0)

// ---------------------------------------------------------------------------
// Split w1/wn into bf16 (hi, mid, lo) triplets: w ≈ hi + mid + lo, residual
// ≤ 2^-24 relative. Layout in wbuf: [w1hi][w1mid][w1lo][wnhi][wnmid][wnlo].
// Also zeroes the g_imp/g_load accumulators (replaces a memset dispatch).
// ---------------------------------------------------------------------------
__global__ __launch_bounds__(256) void wprep_kernel(const float* __restrict__ w1,
                                                    const float* __restrict__ wn,
                                                    __bf16* __restrict__ wbuf,
                                                    float* __restrict__ g_acc)
{
    const int i = blockIdx.x * 256 + threadIdx.x;   // 0..65535
    if (blockIdx.x == 0 && threadIdx.x < 2 * N_EXP) g_acc[threadIdx.x] = 0.f;
    {
        const float v = w1[i];
        const __bf16 h = (__bf16)v;  const float r1 = v - (float)h;
        const __bf16 m = (__bf16)r1; const float r2 = r1 - (float)m;
        wbuf[i] = h; wbuf[WELEM + i] = m; wbuf[2 * WELEM + i] = (__bf16)r2;
    }
    {
        const float v = wn[i];
        const __bf16 h = (__bf16)v;  const float r1 = v - (float)h;
        const __bf16 m = (__bf16)r1; const float r2 = r1 - (float)m;
        wbuf[3 * WELEM + i] = h; wbuf[4 * WELEM + i] = m; wbuf[5 * WELEM + i] = (__bf16)r2;
    }
}

// Triple-split one 8-float x chunk into bf16 hi/mid/lo fragments.
__device__ __forceinline__ void split8(const float4 a, const float4 b,
                                       bf16x8& h, bf16x8& m, bf16x8& l)
{
    const float v[8] = {a.x, a.y, a.z, a.w, b.x, b.y, b.z, b.w};
    #pragma unroll
    for (int j = 0; j < 8; ++j) {
        const float vv = v[j];
        const __bf16 hh = (__bf16)vv;  const float r1 = vv - (float)hh;
        const __bf16 mm = (__bf16)r1;  const float r2 = r1 - (float)mm;
        h[j] = hh; m[j] = mm; l[j] = (__bf16)r2;
    }
}

// ---------------------------------------------------------------------------
// Fused gate kernel: block = 32 tokens (2 tiles), 8 waves (k-split 8 x 512).
// Distance-1 register double-buffer on the x stream (HBM ~900 cyc): buffer
// NXT is issued at the top of each step, buffer CUR (loaded last step) feeds
// split8 with no wait. Weight loads (L2-resident, ~200-400 cyc) issue
// on-demand and hide under the ~160-cyc split VALU. Named A/B buffers +
// fully unrolled x2 body keep indices compile-time (no scratch).
// 24 MFMAs / 4 independent acc chains per step. Grid 512 x 8 waves,
// 2 blocks/CU, 128-VGPR budget via __launch_bounds__(512,4).
// A-frag: A[m=lane&15][k=(lane>>4)*8+j]; B-frag: B[k=(lane>>4)*8+j][n=lane&15];
// C/D: col(token)=lane&15, row(expert)=(lane>>4)*4+reg.   (HW-verified layouts)
// LDS stride 33 floats: store bank = (ml+4q+r)%32 -> max 4-way (was 16-way).
// ---------------------------------------------------------------------------
__global__ __launch_bounds__(512, 4) void gate_kernel(
    const float* __restrict__ x, const __bf16* __restrict__ wbuf,
    const float* __restrict__ w2, const float* __restrict__ noise,
    float* __restrict__ out, float* __restrict__ g_imp, float* __restrict__ g_load)
{
    __shared__ float red[8][TILES][16][33];
    __shared__ float dsum[TILES][16][33];
    __shared__ float s_imp[N_EXP], s_ld[N_EXP];

    const int tid  = threadIdx.x;
    const int lane = tid & 63;
    const int wv   = tid >> 6;      // 0..7 k-split
    const int ml   = lane & 15;     // A-row (expert) / B-col (token-in-tile)
    const int q    = lane >> 4;     // k-group
    const int t0   = blockIdx.x * (TILES * 16);

    const __bf16* w1h = wbuf;
    const __bf16* w1m = wbuf + WELEM;
    const __bf16* w1l = wbuf + 2 * WELEM;
    const __bf16* wnh = wbuf + 3 * WELEM;
    const __bf16* wnm = wbuf + 4 * WELEM;
    const __bf16* wnl = wbuf + 5 * WELEM;

    const size_t xoff0 = (size_t)(t0 + ml) * D_MODEL + wv * 512 + q * 8;
    const size_t xoff1 = xoff0 + (size_t)16 * D_MODEL;
    const int    woff  = ml * D_MODEL + wv * 512 + q * 8;

    f32x4 c1[TILES], c2[TILES];
    #pragma unroll
    for (int tt = 0; tt < TILES; ++tt) {
        c1[tt] = (f32x4){0.f, 0.f, 0.f, 0.f};
        c2[tt] = (f32x4){0.f, 0.f, 0.f, 0.f};
    }

    // x double-buffer registers (named: indices stay compile-time)
    float4 xA0a, xA0b, xA1a, xA1b;
    float4 xB0a, xB0b, xB1a, xB1b;

#define LOADX(P0a, P0b, P1a, P1b, KO)                      \
    P0a = *(const float4*)(x + xoff0 + (KO));              \
    P0b = *(const float4*)(x + xoff0 + (KO) + 4);          \
    P1a = *(const float4*)(x + xoff1 + (KO));              \
    P1b = *(const float4*)(x + xoff1 + (KO) + 4);

#define STEP(C0a, C0b, C1a, C1b, N0a, N0b, N1a, N1b, IT)   \
    {                                                      \
        const int ko = (IT) * 32;                          \
        if ((IT) + 1 < 16) { LOADX(N0a, N0b, N1a, N1b, ko + 32) } \
        const bf16x8 a1h = *(const bf16x8*)(w1h + woff + ko); \
        const bf16x8 a1m = *(const bf16x8*)(w1m + woff + ko); \
        const bf16x8 a1l = *(const bf16x8*)(w1l + woff + ko); \
        const bf16x8 a2h = *(const bf16x8*)(wnh + woff + ko); \
        const bf16x8 a2m = *(const bf16x8*)(wnm + woff + ko); \
        const bf16x8 a2l = *(const bf16x8*)(wnl + woff + ko); \
        bf16x8 xh0, xm0, xl0, xh1, xm1, xl1;               \
        split8(C0a, C0b, xh0, xm0, xl0);                   \
        split8(C1a, C1b, xh1, xm1, xl1);                   \
        c1[0] = MFMA(a1h, xh0, c1[0]);  c2[0] = MFMA(a2h, xh0, c2[0]); \
        c1[1] = MFMA(a1h, xh1, c1[1]);  c2[1] = MFMA(a2h, xh1, c2[1]); \
        c1[0] = MFMA(a1h, xm0, c1[0]);  c2[0] = MFMA(a2h, xm0, c2[0]); \
        c1[1] = MFMA(a1h, xm1, c1[1]);  c2[1] = MFMA(a2h, xm1, c2[1]); \
        c1[0] = MFMA(a1m, xh0, c1[0]);  c2[0] = MFMA(a2m, xh0, c2[0]); \
        c1[1] = MFMA(a1m, xh1, c1[1]);  c2[1] = MFMA(a2m, xh1, c2[1]); \
        c1[0] = MFMA(a1h, xl0, c1[0]);  c2[0] = MFMA(a2h, xl0, c2[0]); \
        c1[1] = MFMA(a1h, xl1, c1[1]);  c2[1] = MFMA(a2h, xl1, c2[1]); \
        c1[0] = MFMA(a1l, xh0, c1[0]);  c2[0] = MFMA(a2l, xh0, c2[0]); \
        c1[1] = MFMA(a1l, xh1, c1[1]);  c2[1] = MFMA(a2l, xh1, c2[1]); \
        c1[0] = MFMA(a1m, xm0, c1[0]);  c2[0] = MFMA(a2m, xm0, c2[0]); \
        c1[1] = MFMA(a1m, xm1, c1[1]);  c2[1] = MFMA(a2m, xm1, c2[1]); \
    }

    LOADX(xA0a, xA0b, xA1a, xA1b, 0)
    #pragma unroll
    for (int ith = 0; ith < 8; ++ith) {
        STEP(xA0a, xA0b, xA1a, xA1b, xB0a, xB0b, xB1a, xB1b, 2 * ith)
        STEP(xB0a, xB0b, xB1a, xB1b, xA0a, xA0b, xA1a, xA1b, 2 * ith + 1)
    }
#undef STEP
#undef LOADX

    #pragma unroll
    for (int tt = 0; tt < TILES; ++tt) {
        #pragma unroll
        for (int r = 0; r < 4; ++r) {
            red[wv][tt][ml][q * 4 + r]      = c1[tt][r];
            red[wv][tt][ml][16 + q * 4 + r] = c2[tt][r];
        }
    }
    __syncthreads();

    // 1024 partial-sum slots, 512 threads: two 8-way reductions each.
    for (int idx = tid; idx < TILES * 512; idx += 512) {
        const int tt = idx >> 9, tk = (idx >> 5) & 15, o = idx & 31;
        float s = 0.f;
        #pragma unroll
        for (int w = 0; w < 8; ++w) s += red[w][tt][tk][o];
        dsum[tt][tk][o] = s;
    }
    if (tid < N_EXP) { s_imp[tid] = 0.f; s_ld[tid] = 0.f; }
    __syncthreads();

    // ---- per-token epilogue on 32 lanes ----
    if (tid < TILES * 16) {
        const int tt = tid >> 4, tk = tid & 15;
        const int t = t0 + tid;
        float dot[32];
        #pragma unroll
        for (int e = 0; e < 32; ++e) dot[e] = dsum[tt][tk][e];

        float th[N_EXP], nc[N_EXP];
        #pragma unroll
        for (int e = 0; e < N_EXP; ++e) th[e] = tanhf(dot[e]);
        #pragma unroll
        for (int e = 0; e < N_EXP; ++e) {
            const float v = dot[N_EXP + e];
            nc[e] = fmaxf(v, 0.f) + log1pf(expf(-fabsf(v))) + 0.01f;
        }

        float lg[N_EXP];
        #pragma unroll
        for (int f = 0; f < N_EXP; ++f) {
            float s = 0.f;
            #pragma unroll
            for (int e = 0; e < N_EXP; ++e) s = fmaf(th[e], w2[f * 16 + e], s);
            lg[f] = s;
        }

        float ln[N_EXP], v[N_EXP];
        {
            const float4* nz = (const float4*)(noise + (size_t)t * 16);
            const float4 n0 = nz[0], n1 = nz[1], n2 = nz[2], n3 = nz[3];
            const float nzv[16] = {n0.x, n0.y, n0.z, n0.w, n1.x, n1.y, n1.z, n1.w,
                                   n2.x, n2.y, n2.z, n2.w, n3.x, n3.y, n3.z, n3.w};
            #pragma unroll
            for (int e = 0; e < N_EXP; ++e) {
                ln[e] = nzv[e] * nc[e];
                v[e]  = lg[e] + ln[e];
            }
        }

        // top-5 selection (ties -> lowest index, matching lax.top_k)
        float tv[5]; int ti[5];
        #pragma unroll
        for (int j = 0; j < 5; ++j) {
            float best = -INFINITY; int bi = 0;
            #pragma unroll
            for (int e = 0; e < N_EXP; ++e) {
                bool taken = false;
                #pragma unroll
                for (int jj = 0; jj < 5; ++jj)
                    if (jj < j) taken = taken || (ti[jj] == e);
                if (!taken && v[e] > best) { best = v[e]; bi = e; }
            }
            tv[j] = best; ti[j] = bi;
        }

        const float mx = tv[0];
        float ex[4], ssum = 0.f;
        #pragma unroll
        for (int j = 0; j < 4; ++j) { ex[j] = expf(tv[j] - mx); ssum += ex[j]; }
        const float inv = 1.f / ssum;
        float sc[4];
        #pragma unroll
        for (int j = 0; j < 4; ++j) sc[j] = ex[j] * inv;

        #pragma unroll
        for (int j = 0; j < 4; ++j) atomicAdd(&s_imp[ti[j]], sc[j]);

        const float thr_in = tv[4], thr_out = tv[3];
        #pragma unroll
        for (int e = 0; e < N_EXP; ++e) {
            const bool  is_in = ln[e] > thr_in;
            const float thr   = is_in ? thr_in : thr_out;
            const float z     = (lg[e] - thr) / nc[e];
            const float prob  = 0.5f * (1.f + erff(z * 0.70710678118654752f));
            atomicAdd(&s_ld[e], prob);
        }

        ((float4*)out)[t] = make_float4((float)ti[0], (float)ti[1],
                                        (float)ti[2], (float)ti[3]);
        ((float4*)(out + N_TOK * N_SEL))[t] = make_float4(sc[0], sc[1], sc[2], sc[3]);
    }
    __syncthreads();
    if (tid < N_EXP)            atomicAdd(&g_imp[tid], s_imp[tid]);
    else if (tid < 2 * N_EXP)   atomicAdd(&g_load[tid - N_EXP], s_ld[tid - N_EXP]);
}

// ---------------------------------------------------------------------------
// gate loss = lambda * (cv2(importance) + cv2(load))
// ---------------------------------------------------------------------------
__global__ void loss_kernel(const float* __restrict__ g_imp,
                            const float* __restrict__ g_load,
                            float* __restrict__ out)
{
    if (threadIdx.x == 0 && blockIdx.x == 0) {
        double mi = 0.0, ml = 0.0;
        for (int e = 0; e < N_EXP; ++e) { mi += g_imp[e]; ml += g_load[e]; }
        mi /= N_EXP; ml /= N_EXP;
        double vi = 0.0, vl = 0.0;
        for (int e = 0; e < N_EXP; ++e) {
            const double di = g_imp[e] - mi;  vi += di * di;
            const double dl = g_load[e] - ml; vl += dl * dl;
        }
        vi /= (N_EXP - 1); vl /= (N_EXP - 1);
        const double ci = vi / (mi * mi + 1e-10);
        const double cl = vl / (ml * ml + 1e-10);
        out[N_TOK * N_SEL * 2] = (float)(0.01 * (ci + cl));
    }
}

// ---------------------------------------------------------------------------
extern "C" void kernel_launch(void* const* d_in, const int* in_sizes, int n_in,
                              void* d_out, int out_size, void* d_ws, size_t ws_size,
                              hipStream_t stream)
{
    const float* x     = (const float*)d_in[0];
    const float* w1    = (const float*)d_in[1];
    const float* w2    = (const float*)d_in[2];
    const float* wn    = (const float*)d_in[3];
    const float* noise = (const float*)d_in[4];
    float* out = (float*)d_out;

    __bf16* wbuf  = (__bf16*)d_ws;                              // 6*65536 bf16 = 768 KB
    float*  g_imp = (float*)((char*)d_ws + (1 << 20));          // 32 floats @ 1 MB
    float*  g_load = g_imp + N_EXP;

    wprep_kernel<<<WELEM / 256, 256, 0, stream>>>(w1, wn, wbuf, g_imp);
    gate_kernel<<<N_TOK / (TILES * 16), 512, 0, stream>>>(x, wbuf, w2, noise, out,
                                                          g_imp, g_load);
    loss_kernel<<<1, 64, 0, stream>>>(g_imp, g_load, out);
}

// Round 4
// 415.705 us; speedup vs baseline: 1.0035x; 1.0035x over previous
//
#include <hip/hip_runtime.h>
#include <math.h>

#define N_TOK   16384
#define D_MODEL 4096
#define N_EXP   16
#define N_SEL   4
#define WELEM   (N_EXP * D_MODEL)   // 65536 per weight matrix
#define TILES   4                   // token tiles per block (64 tokens)

typedef __bf16 bf16x8 __attribute__((ext_vector_type(8)));
typedef float  f32x4  __attribute__((ext_vector_type(4)));

#define MFMA(a, b, c) __builtin_amdgcn_mfma_f32_16x16x32_bf16((a), (b), (c), 0, 0, 0)

// ---------------------------------------------------------------------------
// Split w1/wn into bf16 (hi, mid, lo) triplets: w ≈ hi + mid + lo, residual
// ≤ 2^-24 relative. Layout in wbuf: [w1hi][w1mid][w1lo][wnhi][wnmid][wnlo].
// Also zeroes the g_imp/g_load accumulators (replaces a memset dispatch).
// ---------------------------------------------------------------------------
__global__ __launch_bounds__(256) void wprep_kernel(const float* __restrict__ w1,
                                                    const float* __restrict__ wn,
                                                    __bf16* __restrict__ wbuf,
                                                    float* __restrict__ g_acc)
{
    const int i = blockIdx.x * 256 + threadIdx.x;   // 0..65535
    if (blockIdx.x == 0 && threadIdx.x < 2 * N_EXP) g_acc[threadIdx.x] = 0.f;
    {
        const float v = w1[i];
        const __bf16 h = (__bf16)v;  const float r1 = v - (float)h;
        const __bf16 m = (__bf16)r1; const float r2 = r1 - (float)m;
        wbuf[i] = h; wbuf[WELEM + i] = m; wbuf[2 * WELEM + i] = (__bf16)r2;
    }
    {
        const float v = wn[i];
        const __bf16 h = (__bf16)v;  const float r1 = v - (float)h;
        const __bf16 m = (__bf16)r1; const float r2 = r1 - (float)m;
        wbuf[3 * WELEM + i] = h; wbuf[4 * WELEM + i] = m; wbuf[5 * WELEM + i] = (__bf16)r2;
    }
}

// Triple-split one 8-float x chunk into bf16 hi/mid/lo fragments.
__device__ __forceinline__ void split8(const float4 a, const float4 b,
                                       bf16x8& h, bf16x8& m, bf16x8& l)
{
    const float v[8] = {a.x, a.y, a.z, a.w, b.x, b.y, b.z, b.w};
    #pragma unroll
    for (int j = 0; j < 8; ++j) {
        const float vv = v[j];
        const __bf16 hh = (__bf16)vv;  const float r1 = vv - (float)hh;
        const __bf16 mm = (__bf16)r1;  const float r2 = r1 - (float)mm;
        h[j] = hh; m[j] = mm; l[j] = (__bf16)r2;
    }
}

// ---------------------------------------------------------------------------
// Fused gate kernel: block = 64 tokens (4 tiles), 8 waves (k-split 8 x 512).
// THEORY (fits rounds 0-3): divergent 16B/lane loads cost ~64 TA cycles each
// regardless of resident waves -> vector-mem ISSUE-throughput bound. Levers:
// fewer load instrs per token + fewer bytes per CU. TILES=4, grid=256
// (1 block/CU): weights stream through each CU ONCE (768 KB vs 1.5 MB),
// 14 loads/iter feed 48 MFMAs (8 independent acc chains). On-demand loads
// (round-3 explicit dbuf regressed). 128-VGPR budget via launch_bounds(512,4).
// A-frag: A[m=lane&15][k=(lane>>4)*8+j]; B-frag: B[k=(lane>>4)*8+j][n=lane&15];
// C/D: col(token)=lane&15, row(expert)=(lane>>4)*4+reg.   (HW-verified layouts)
// LDS stride 33 floats: store bank = (ml+4q+r)%32 -> max 4-way conflict.
// ---------------------------------------------------------------------------
__global__ __launch_bounds__(512, 4) void gate_kernel(
    const float* __restrict__ x, const __bf16* __restrict__ wbuf,
    const float* __restrict__ w2, const float* __restrict__ noise,
    float* __restrict__ out, float* __restrict__ g_imp, float* __restrict__ g_load)
{
    __shared__ float red[8][TILES][16][33];
    __shared__ float dsum[TILES][16][33];
    __shared__ float s_imp[N_EXP], s_ld[N_EXP];

    const int tid  = threadIdx.x;
    const int lane = tid & 63;
    const int wv   = tid >> 6;      // 0..7 k-split
    const int ml   = lane & 15;     // A-row (expert) / B-col (token-in-tile)
    const int q    = lane >> 4;     // k-group
    const int t0   = blockIdx.x * (TILES * 16);

    const __bf16* w1h = wbuf;
    const __bf16* w1m = wbuf + WELEM;
    const __bf16* w1l = wbuf + 2 * WELEM;
    const __bf16* wnh = wbuf + 3 * WELEM;
    const __bf16* wnm = wbuf + 4 * WELEM;
    const __bf16* wnl = wbuf + 5 * WELEM;

    const size_t xoff0 = (size_t)(t0 + ml) * D_MODEL + wv * 512 + q * 8;
    const int    woff  = ml * D_MODEL + wv * 512 + q * 8;

    f32x4 c1[TILES], c2[TILES];
    #pragma unroll
    for (int tt = 0; tt < TILES; ++tt) {
        c1[tt] = (f32x4){0.f, 0.f, 0.f, 0.f};
        c2[tt] = (f32x4){0.f, 0.f, 0.f, 0.f};
    }

    #pragma unroll 2
    for (int it = 0; it < 16; ++it) {
        const int ko = it * 32;
        // ---- issue all 14 loads first ----
        const bf16x8 a1h = *(const bf16x8*)(w1h + woff + ko);
        const bf16x8 a1m = *(const bf16x8*)(w1m + woff + ko);
        const bf16x8 a1l = *(const bf16x8*)(w1l + woff + ko);
        const bf16x8 a2h = *(const bf16x8*)(wnh + woff + ko);
        const bf16x8 a2m = *(const bf16x8*)(wnm + woff + ko);
        const bf16x8 a2l = *(const bf16x8*)(wnl + woff + ko);
        float4 xa[TILES], xb[TILES];
        #pragma unroll
        for (int tt = 0; tt < TILES; ++tt) {
            const size_t xo = xoff0 + (size_t)(16 * tt) * D_MODEL + ko;
            xa[tt] = *(const float4*)(x + xo);
            xb[tt] = *(const float4*)(x + xo + 4);
        }

        // ---- split + 12 MFMAs per tile (8 independent acc chains total) ----
        #pragma unroll
        for (int tt = 0; tt < TILES; ++tt) {
            bf16x8 xh, xm8, xl;
            split8(xa[tt], xb[tt], xh, xm8, xl);
            c1[tt] = MFMA(a1h, xh, c1[tt]);   c2[tt] = MFMA(a2h, xh, c2[tt]);
            c1[tt] = MFMA(a1h, xm8, c1[tt]);  c2[tt] = MFMA(a2h, xm8, c2[tt]);
            c1[tt] = MFMA(a1m, xh, c1[tt]);   c2[tt] = MFMA(a2m, xh, c2[tt]);
            c1[tt] = MFMA(a1h, xl, c1[tt]);   c2[tt] = MFMA(a2h, xl, c2[tt]);
            c1[tt] = MFMA(a1l, xh, c1[tt]);   c2[tt] = MFMA(a2l, xh, c2[tt]);
            c1[tt] = MFMA(a1m, xm8, c1[tt]);  c2[tt] = MFMA(a2m, xm8, c2[tt]);
        }
    }

    #pragma unroll
    for (int tt = 0; tt < TILES; ++tt) {
        #pragma unroll
        for (int r = 0; r < 4; ++r) {
            red[wv][tt][ml][q * 4 + r]      = c1[tt][r];
            red[wv][tt][ml][16 + q * 4 + r] = c2[tt][r];
        }
    }
    __syncthreads();

    // 2048 partial-sum slots, 512 threads: four 8-way reductions each.
    for (int idx = tid; idx < TILES * 512; idx += 512) {
        const int tt = idx >> 9, tk = (idx >> 5) & 15, o = idx & 31;
        float s = 0.f;
        #pragma unroll
        for (int w = 0; w < 8; ++w) s += red[w][tt][tk][o];
        dsum[tt][tk][o] = s;
    }
    if (tid < N_EXP) { s_imp[tid] = 0.f; s_ld[tid] = 0.f; }
    __syncthreads();

    // ---- per-token epilogue on 64 lanes (one full wave) ----
    if (tid < TILES * 16) {
        const int tt = tid >> 4, tk = tid & 15;
        const int t = t0 + tid;
        float dot[32];
        #pragma unroll
        for (int e = 0; e < 32; ++e) dot[e] = dsum[tt][tk][e];

        float th[N_EXP], nc[N_EXP];
        #pragma unroll
        for (int e = 0; e < N_EXP; ++e) th[e] = tanhf(dot[e]);
        #pragma unroll
        for (int e = 0; e < N_EXP; ++e) {
            const float v = dot[N_EXP + e];
            nc[e] = fmaxf(v, 0.f) + log1pf(expf(-fabsf(v))) + 0.01f;
        }

        float lg[N_EXP];
        #pragma unroll
        for (int f = 0; f < N_EXP; ++f) {
            float s = 0.f;
            #pragma unroll
            for (int e = 0; e < N_EXP; ++e) s = fmaf(th[e], w2[f * 16 + e], s);
            lg[f] = s;
        }

        float ln[N_EXP], v[N_EXP];
        {
            const float4* nz = (const float4*)(noise + (size_t)t * 16);
            const float4 n0 = nz[0], n1 = nz[1], n2 = nz[2], n3 = nz[3];
            const float nzv[16] = {n0.x, n0.y, n0.z, n0.w, n1.x, n1.y, n1.z, n1.w,
                                   n2.x, n2.y, n2.z, n2.w, n3.x, n3.y, n3.z, n3.w};
            #pragma unroll
            for (int e = 0; e < N_EXP; ++e) {
                ln[e] = nzv[e] * nc[e];
                v[e]  = lg[e] + ln[e];
            }
        }

        // top-5 selection (ties -> lowest index, matching lax.top_k)
        float tv[5]; int ti[5];
        #pragma unroll
        for (int j = 0; j < 5; ++j) {
            float best = -INFINITY; int bi = 0;
            #pragma unroll
            for (int e = 0; e < N_EXP; ++e) {
                bool taken = false;
                #pragma unroll
                for (int jj = 0; jj < 5; ++jj)
                    if (jj < j) taken = taken || (ti[jj] == e);
                if (!taken && v[e] > best) { best = v[e]; bi = e; }
            }
            tv[j] = best; ti[j] = bi;
        }

        const float mx = tv[0];
        float ex[4], ssum = 0.f;
        #pragma unroll
        for (int j = 0; j < 4; ++j) { ex[j] = expf(tv[j] - mx); ssum += ex[j]; }
        const float inv = 1.f / ssum;
        float sc[4];
        #pragma unroll
        for (int j = 0; j < 4; ++j) sc[j] = ex[j] * inv;

        #pragma unroll
        for (int j = 0; j < 4; ++j) atomicAdd(&s_imp[ti[j]], sc[j]);

        const float thr_in = tv[4], thr_out = tv[3];
        #pragma unroll
        for (int e = 0; e < N_EXP; ++e) {
            const bool  is_in = ln[e] > thr_in;
            const float thr   = is_in ? thr_in : thr_out;
            const float z     = (lg[e] - thr) / nc[e];
            const float prob  = 0.5f * (1.f + erff(z * 0.70710678118654752f));
            atomicAdd(&s_ld[e], prob);
        }

        ((float4*)out)[t] = make_float4((float)ti[0], (float)ti[1],
                                        (float)ti[2], (float)ti[3]);
        ((float4*)(out + N_TOK * N_SEL))[t] = make_float4(sc[0], sc[1], sc[2], sc[3]);
    }
    __syncthreads();
    if (tid < N_EXP)            atomicAdd(&g_imp[tid], s_imp[tid]);
    else if (tid < 2 * N_EXP)   atomicAdd(&g_load[tid - N_EXP], s_ld[tid - N_EXP]);
}

// ---------------------------------------------------------------------------
// gate loss = lambda * (cv2(importance) + cv2(load))
// ---------------------------------------------------------------------------
__global__ void loss_kernel(const float* __restrict__ g_imp,
                            const float* __restrict__ g_load,
                            float* __restrict__ out)
{
    if (threadIdx.x == 0 && blockIdx.x == 0) {
        double mi = 0.0, ml = 0.0;
        for (int e = 0; e < N_EXP; ++e) { mi += g_imp[e]; ml += g_load[e]; }
        mi /= N_EXP; ml /= N_EXP;
        double vi = 0.0, vl = 0.0;
        for (int e = 0; e < N_EXP; ++e) {
            const double di = g_imp[e] - mi;  vi += di * di;
            const double dl = g_load[e] - ml; vl += dl * dl;
        }
        vi /= (N_EXP - 1); vl /= (N_EXP - 1);
        const double ci = vi / (mi * mi + 1e-10);
        const double cl = vl / (ml * ml + 1e-10);
        out[N_TOK * N_SEL * 2] = (float)(0.01 * (ci + cl));
    }
}

// ---------------------------------------------------------------------------
extern "C" void kernel_launch(void* const* d_in, const int* in_sizes, int n_in,
                              void* d_out, int out_size, void* d_ws, size_t ws_size,
                              hipStream_t stream)
{
    const float* x     = (const float*)d_in[0];
    const float* w1    = (const float*)d_in[1];
    const float* w2    = (const float*)d_in[2];
    const float* wn    = (const float*)d_in[3];
    const float* noise = (const float*)d_in[4];
    float* out = (float*)d_out;

    __bf16* wbuf  = (__bf16*)d_ws;                              // 6*65536 bf16 = 768 KB
    float*  g_imp = (float*)((char*)d_ws + (1 << 20));          // 32 floats @ 1 MB
    float*  g_load = g_imp + N_EXP;

    wprep_kernel<<<WELEM / 256, 256, 0, stream>>>(w1, wn, wbuf, g_imp);
    gate_kernel<<<N_TOK / (TILES * 16), 512, 0, stream>>>(x, wbuf, w2, noise, out,
                                                          g_imp, g_load);
    loss_kernel<<<1, 64, 0, stream>>>(g_imp, g_load, out);
}

// Round 5
// 405.749 us; speedup vs baseline: 1.0281x; 1.0245x over previous
//
#include <hip/hip_runtime.h>
#include <math.h>

#define N_TOK   16384
#define D_MODEL 4096
#define N_EXP   16
#define N_SEL   4
#define WELEM   (N_EXP * D_MODEL)   // 65536 per weight matrix
#define TILES   2                   // token tiles per block (32 tokens)

typedef __bf16 bf16x8 __attribute__((ext_vector_type(8)));
typedef float  f32x4  __attribute__((ext_vector_type(4)));

#define MFMA(a, b, c) __builtin_amdgcn_mfma_f32_16x16x32_bf16((a), (b), (c), 0, 0, 0)

// ---------------------------------------------------------------------------
// Split w1/wn into bf16 (hi, mid, lo) triplets: w ≈ hi + mid + lo, residual
// ≤ 2^-24 relative. Layout in wbuf: [w1hi][w1mid][w1lo][wnhi][wnmid][wnlo].
// Also zeroes the g_imp/g_load accumulators (replaces a memset dispatch).
// ---------------------------------------------------------------------------
__global__ __launch_bounds__(256) void wprep_kernel(const float* __restrict__ w1,
                                                    const float* __restrict__ wn,
                                                    __bf16* __restrict__ wbuf,
                                                    float* __restrict__ g_acc)
{
    const int i = blockIdx.x * 256 + threadIdx.x;   // 0..65535
    if (blockIdx.x == 0 && threadIdx.x < 2 * N_EXP) g_acc[threadIdx.x] = 0.f;
    {
        const float v = w1[i];
        const __bf16 h = (__bf16)v;  const float r1 = v - (float)h;
        const __bf16 m = (__bf16)r1; const float r2 = r1 - (float)m;
        wbuf[i] = h; wbuf[WELEM + i] = m; wbuf[2 * WELEM + i] = (__bf16)r2;
    }
    {
        const float v = wn[i];
        const __bf16 h = (__bf16)v;  const float r1 = v - (float)h;
        const __bf16 m = (__bf16)r1; const float r2 = r1 - (float)m;
        wbuf[3 * WELEM + i] = h; wbuf[4 * WELEM + i] = m; wbuf[5 * WELEM + i] = (__bf16)r2;
    }
}

// Triple-split one 8-float x chunk into bf16 hi/mid/lo fragments.
__device__ __forceinline__ void split8(const float4 a, const float4 b,
                                       bf16x8& h, bf16x8& m, bf16x8& l)
{
    const float v[8] = {a.x, a.y, a.z, a.w, b.x, b.y, b.z, b.w};
    #pragma unroll
    for (int j = 0; j < 8; ++j) {
        const float vv = v[j];
        const __bf16 hh = (__bf16)vv;  const float r1 = vv - (float)hh;
        const __bf16 mm = (__bf16)r1;  const float r2 = r1 - (float)mm;
        h[j] = hh; m[j] = mm; l[j] = (__bf16)r2;
    }
}

// ---------------------------------------------------------------------------
// Fused gate kernel: block = 32 tokens, 8 waves (k-split 8 x 512), grid 512.
// THEORY (round 5): the per-wave x loads (16 rows @ 16 KB stride, 16 B/row)
// destroy DRAM page locality chip-wide -> effective ~1 TB/s vs 6.7 TB/s for
// sequential streams. Fix: cooperative COALESCED staging of x into LDS.
// Per k-chunk (32 floats/token/region): 512 threads load 32 KB as dense
// 128-B runs (8 thr/run) into a double-buffered LDS tile [8r][32t][33pad]
// (stride 33: <=2-way bank conflicts on write AND read = free, m136).
// Issue order per iter: weights -> stage loads (chunk i+1) -> ds_read/split/
// MFMA (weight-wait leaves stage loads in flight, FIFO) -> ds_write -> bar.
// One barrier/iter; stage HBM latency hides under split+MFMA (T14).
// LDS buffers reused post-loop for red/dsum (67.7 KB -> 2 blocks/CU).
// Numerics bitwise-identical to round 2 (same splits, same MFMA order).
// A-frag: A[m=lane&15][k=(lane>>4)*8+j]; B-frag: B[k=(lane>>4)*8+j][n=lane&15];
// C/D: col(token)=lane&15, row(expert)=(lane>>4)*4+reg.   (HW-verified layouts)
// ---------------------------------------------------------------------------
__global__ __launch_bounds__(512, 4) void gate_kernel(
    const float* __restrict__ x, const __bf16* __restrict__ wbuf,
    const float* __restrict__ w2, const float* __restrict__ noise,
    float* __restrict__ out, float* __restrict__ g_imp, float* __restrict__ g_load)
{
    // Two 8448-float buffers: x k-chunk staging (double-buffered), then
    // reused post-loop as red (buf0) and dsum (buf1).
    __shared__ float smem[2][8 * 32 * 33];
    __shared__ float s_imp[N_EXP], s_ld[N_EXP];

    const int tid  = threadIdx.x;
    const int lane = tid & 63;
    const int wv   = tid >> 6;      // 0..7 k-region
    const int ml   = lane & 15;     // A-row (expert) / B-col (token-in-tile)
    const int q    = lane >> 4;     // k-group
    const int t0   = blockIdx.x * (TILES * 16);

    const __bf16* w1h = wbuf;
    const __bf16* w1m = wbuf + WELEM;
    const __bf16* w1l = wbuf + 2 * WELEM;
    const __bf16* wnh = wbuf + 3 * WELEM;
    const __bf16* wnm = wbuf + 4 * WELEM;
    const __bf16* wnl = wbuf + 5 * WELEM;

    const int woff = ml * D_MODEL + wv * 512 + q * 8;

    // ---- staging map: fid = p*512+tid; slot=fid&7 (16B within 128B run),
    //      s=fid>>3 (seg), r=s>>5 (k-region), t=s&31 (token).
    //      8 consecutive threads load one dense 128-B run.  ----
    int gb0, gb1, gb2, gb3, lb0, lb1, lb2, lb3;
    {
#define MAP(P, GB, LB)                                           \
        {   const int fid  = (P) * 512 + tid;                    \
            const int slot = fid & 7;                            \
            const int s    = fid >> 3;                           \
            const int r    = s >> 5;                             \
            const int t    = s & 31;                             \
            GB = (t0 + t) * D_MODEL + r * 512 + slot * 4;        \
            LB = (r * 32 + t) * 33 + slot * 4;  }
        MAP(0, gb0, lb0) MAP(1, gb1, lb1) MAP(2, gb2, lb2) MAP(3, gb3, lb3)
#undef MAP
    }
    // consume offsets: wave wv reads LDS rows (wv*32+ml) and (+16), cols q*8..
    const int lr0 = (wv * 32 + ml) * 33 + q * 8;
    const int lr1 = lr0 + 16 * 33;

    f32x4 c1[TILES], c2[TILES];
    #pragma unroll
    for (int tt = 0; tt < TILES; ++tt) {
        c1[tt] = (f32x4){0.f, 0.f, 0.f, 0.f};
        c2[tt] = (f32x4){0.f, 0.f, 0.f, 0.f};
    }

    float* bufA = smem[0];
    float* bufB = smem[1];

    {   // prologue: stage chunk 0 into bufA
        const float4 s0 = *(const float4*)(x + gb0);
        const float4 s1 = *(const float4*)(x + gb1);
        const float4 s2 = *(const float4*)(x + gb2);
        const float4 s3 = *(const float4*)(x + gb3);
        *(float4*)(bufA + lb0) = s0;
        *(float4*)(bufA + lb1) = s1;
        *(float4*)(bufA + lb2) = s2;
        *(float4*)(bufA + lb3) = s3;
        __syncthreads();
    }

#define STEP(CUR, NXT, IT)                                                    \
    {                                                                          \
        const int ko = (IT) * 32;                                              \
        const bf16x8 a1h = *(const bf16x8*)(w1h + woff + ko);                  \
        const bf16x8 a1m = *(const bf16x8*)(w1m + woff + ko);                  \
        const bf16x8 a1l = *(const bf16x8*)(w1l + woff + ko);                  \
        const bf16x8 a2h = *(const bf16x8*)(wnh + woff + ko);                  \
        const bf16x8 a2m = *(const bf16x8*)(wnm + woff + ko);                  \
        const bf16x8 a2l = *(const bf16x8*)(wnl + woff + ko);                  \
        float4 sg0, sg1, sg2, sg3;                                             \
        if ((IT) < 15) {                                                       \
            const int co = ((IT) + 1) * 32;                                    \
            sg0 = *(const float4*)(x + gb0 + co);                              \
            sg1 = *(const float4*)(x + gb1 + co);                              \
            sg2 = *(const float4*)(x + gb2 + co);                              \
            sg3 = *(const float4*)(x + gb3 + co);                              \
        }                                                                      \
        const float4 xa0 = *(const float4*)((CUR) + lr0);                      \
        const float4 xb0 = *(const float4*)((CUR) + lr0 + 4);                  \
        const float4 xa1 = *(const float4*)((CUR) + lr1);                      \
        const float4 xb1 = *(const float4*)((CUR) + lr1 + 4);                  \
        bf16x8 xh0, xm0, xl0, xh1, xm1, xl1;                                   \
        split8(xa0, xb0, xh0, xm0, xl0);                                       \
        split8(xa1, xb1, xh1, xm1, xl1);                                       \
        c1[0] = MFMA(a1h, xh0, c1[0]);  c2[0] = MFMA(a2h, xh0, c2[0]);         \
        c1[1] = MFMA(a1h, xh1, c1[1]);  c2[1] = MFMA(a2h, xh1, c2[1]);         \
        c1[0] = MFMA(a1h, xm0, c1[0]);  c2[0] = MFMA(a2h, xm0, c2[0]);         \
        c1[1] = MFMA(a1h, xm1, c1[1]);  c2[1] = MFMA(a2h, xm1, c2[1]);         \
        c1[0] = MFMA(a1m, xh0, c1[0]);  c2[0] = MFMA(a2m, xh0, c2[0]);         \
        c1[1] = MFMA(a1m, xh1, c1[1]);  c2[1] = MFMA(a2m, xh1, c2[1]);         \
        c1[0] = MFMA(a1h, xl0, c1[0]);  c2[0] = MFMA(a2h, xl0, c2[0]);         \
        c1[1] = MFMA(a1h, xl1, c1[1]);  c2[1] = MFMA(a2h, xl1, c2[1]);         \
        c1[0] = MFMA(a1l, xh0, c1[0]);  c2[0] = MFMA(a2l, xh0, c2[0]);         \
        c1[1] = MFMA(a1l, xh1, c1[1]);  c2[1] = MFMA(a2l, xh1, c2[1]);         \
        c1[0] = MFMA(a1m, xm0, c1[0]);  c2[0] = MFMA(a2m, xm0, c2[0]);         \
        c1[1] = MFMA(a1m, xm1, c1[1]);  c2[1] = MFMA(a2m, xm1, c2[1]);         \
        if ((IT) < 15) {                                                       \
            *(float4*)((NXT) + lb0) = sg0;                                     \
            *(float4*)((NXT) + lb1) = sg1;                                     \
            *(float4*)((NXT) + lb2) = sg2;                                     \
            *(float4*)((NXT) + lb3) = sg3;                                     \
        }                                                                      \
        __syncthreads();                                                       \
    }

    #pragma unroll
    for (int ith = 0; ith < 8; ++ith) {
        STEP(bufA, bufB, 2 * ith)
        STEP(bufB, bufA, 2 * ith + 1)
    }
#undef STEP

    // ---- reuse staging LDS: red = buf0 [8][2][16][33], dsum = buf1 [2][16][33]
    float* red  = smem[0];
    float* dsum = smem[1];

    #pragma unroll
    for (int tt = 0; tt < TILES; ++tt) {
        #pragma unroll
        for (int r = 0; r < 4; ++r) {
            red[((wv * TILES + tt) * 16 + ml) * 33 + q * 4 + r]      = c1[tt][r];
            red[((wv * TILES + tt) * 16 + ml) * 33 + 16 + q * 4 + r] = c2[tt][r];
        }
    }
    __syncthreads();

    // 1024 partial-sum slots, 512 threads: two 8-way reductions each.
    for (int idx = tid; idx < TILES * 512; idx += 512) {
        const int tt = idx >> 9, tk = (idx >> 5) & 15, o = idx & 31;
        float s = 0.f;
        #pragma unroll
        for (int w = 0; w < 8; ++w) s += red[((w * TILES + tt) * 16 + tk) * 33 + o];
        dsum[(tt * 16 + tk) * 33 + o] = s;
    }
    if (tid < N_EXP) { s_imp[tid] = 0.f; s_ld[tid] = 0.f; }
    __syncthreads();

    // ---- per-token epilogue on 32 lanes ----
    if (tid < TILES * 16) {
        const int tt = tid >> 4, tk = tid & 15;
        const int t = t0 + tid;
        float dot[32];
        #pragma unroll
        for (int e = 0; e < 32; ++e) dot[e] = dsum[(tt * 16 + tk) * 33 + e];

        float th[N_EXP], nc[N_EXP];
        #pragma unroll
        for (int e = 0; e < N_EXP; ++e) th[e] = tanhf(dot[e]);
        #pragma unroll
        for (int e = 0; e < N_EXP; ++e) {
            const float v = dot[N_EXP + e];
            nc[e] = fmaxf(v, 0.f) + log1pf(expf(-fabsf(v))) + 0.01f;
        }

        float lg[N_EXP];
        #pragma unroll
        for (int f = 0; f < N_EXP; ++f) {
            float s = 0.f;
            #pragma unroll
            for (int e = 0; e < N_EXP; ++e) s = fmaf(th[e], w2[f * 16 + e], s);
            lg[f] = s;
        }

        float ln[N_EXP], v[N_EXP];
        {
            const float4* nz = (const float4*)(noise + (size_t)t * 16);
            const float4 n0 = nz[0], n1 = nz[1], n2 = nz[2], n3 = nz[3];
            const float nzv[16] = {n0.x, n0.y, n0.z, n0.w, n1.x, n1.y, n1.z, n1.w,
                                   n2.x, n2.y, n2.z, n2.w, n3.x, n3.y, n3.z, n3.w};
            #pragma unroll
            for (int e = 0; e < N_EXP; ++e) {
                ln[e] = nzv[e] * nc[e];
                v[e]  = lg[e] + ln[e];
            }
        }

        // top-5 selection (ties -> lowest index, matching lax.top_k)
        float tv[5]; int ti[5];
        #pragma unroll
        for (int j = 0; j < 5; ++j) {
            float best = -INFINITY; int bi = 0;
            #pragma unroll
            for (int e = 0; e < N_EXP; ++e) {
                bool taken = false;
                #pragma unroll
                for (int jj = 0; jj < 5; ++jj)
                    if (jj < j) taken = taken || (ti[jj] == e);
                if (!taken && v[e] > best) { best = v[e]; bi = e; }
            }
            tv[j] = best; ti[j] = bi;
        }

        const float mx = tv[0];
        float ex[4], ssum = 0.f;
        #pragma unroll
        for (int j = 0; j < 4; ++j) { ex[j] = expf(tv[j] - mx); ssum += ex[j]; }
        const float inv = 1.f / ssum;
        float sc[4];
        #pragma unroll
        for (int j = 0; j < 4; ++j) sc[j] = ex[j] * inv;

        #pragma unroll
        for (int j = 0; j < 4; ++j) atomicAdd(&s_imp[ti[j]], sc[j]);

        const float thr_in = tv[4], thr_out = tv[3];
        #pragma unroll
        for (int e = 0; e < N_EXP; ++e) {
            const bool  is_in = ln[e] > thr_in;
            const float thr   = is_in ? thr_in : thr_out;
            const float z     = (lg[e] - thr) / nc[e];
            const float prob  = 0.5f * (1.f + erff(z * 0.70710678118654752f));
            atomicAdd(&s_ld[e], prob);
        }

        ((float4*)out)[t] = make_float4((float)ti[0], (float)ti[1],
                                        (float)ti[2], (float)ti[3]);
        ((float4*)(out + N_TOK * N_SEL))[t] = make_float4(sc[0], sc[1], sc[2], sc[3]);
    }
    __syncthreads();
    if (tid < N_EXP)            atomicAdd(&g_imp[tid], s_imp[tid]);
    else if (tid < 2 * N_EXP)   atomicAdd(&g_load[tid - N_EXP], s_ld[tid - N_EXP]);
}

// ---------------------------------------------------------------------------
// gate loss = lambda * (cv2(importance) + cv2(load))
// ---------------------------------------------------------------------------
__global__ void loss_kernel(const float* __restrict__ g_imp,
                            const float* __restrict__ g_load,
                            float* __restrict__ out)
{
    if (threadIdx.x == 0 && blockIdx.x == 0) {
        double mi = 0.0, ml = 0.0;
        for (int e = 0; e < N_EXP; ++e) { mi += g_imp[e]; ml += g_load[e]; }
        mi /= N_EXP; ml /= N_EXP;
        double vi = 0.0, vl = 0.0;
        for (int e = 0; e < N_EXP; ++e) {
            const double di = g_imp[e] - mi;  vi += di * di;
            const double dl = g_load[e] - ml; vl += dl * dl;
        }
        vi /= (N_EXP - 1); vl /= (N_EXP - 1);
        const double ci = vi / (mi * mi + 1e-10);
        const double cl = vl / (ml * ml + 1e-10);
        out[N_TOK * N_SEL * 2] = (float)(0.01 * (ci + cl));
    }
}

// ---------------------------------------------------------------------------
extern "C" void kernel_launch(void* const* d_in, const int* in_sizes, int n_in,
                              void* d_out, int out_size, void* d_ws, size_t ws_size,
                              hipStream_t stream)
{
    const float* x     = (const float*)d_in[0];
    const float* w1    = (const float*)d_in[1];
    const float* w2    = (const float*)d_in[2];
    const float* wn    = (const float*)d_in[3];
    const float* noise = (const float*)d_in[4];
    float* out = (float*)d_out;

    __bf16* wbuf  = (__bf16*)d_ws;                              // 6*65536 bf16 = 768 KB
    float*  g_imp = (float*)((char*)d_ws + (1 << 20));          // 32 floats @ 1 MB
    float*  g_load = g_imp + N_EXP;

    wprep_kernel<<<WELEM / 256, 256, 0, stream>>>(w1, wn, wbuf, g_imp);
    gate_kernel<<<N_TOK / (TILES * 16), 512, 0, stream>>>(x, wbuf, w2, noise, out,
                                                          g_imp, g_load);
    loss_kernel<<<1, 64, 0, stream>>>(g_imp, g_load, out);
}

// Round 6
// 401.227 us; speedup vs baseline: 1.0397x; 1.0113x over previous
//
#include <hip/hip_runtime.h>
#include <math.h>

#define N_TOK   16384
#define D_MODEL 4096
#define N_EXP   16
#define N_SEL   4
#define WELEM   (N_EXP * D_MODEL)   // 65536 per weight matrix
#define TILES   2                   // token tiles per block (32 tokens)
#define NWIN    16                  // k-windows
#define WINF    256                 // floats per token per window (1 KB run)
#define TSTR    260                 // padded words per token row in window buf
#define BUFW    (32 * TSTR)         // 8320 words per staging buffer

typedef __bf16 bf16x8 __attribute__((ext_vector_type(8)));
typedef float  f32x4  __attribute__((ext_vector_type(4)));

#define MFMA(a, b, c) __builtin_amdgcn_mfma_f32_16x16x32_bf16((a), (b), (c), 0, 0, 0)

// ---------------------------------------------------------------------------
// Split w1/wn into bf16 (hi, mid, lo) triplets: w ≈ hi + mid + lo, residual
// ≤ 2^-24 relative. Layout in wbuf: [w1hi][w1mid][w1lo][wnhi][wnmid][wnlo].
// Also zeroes the g_imp/g_load accumulators (replaces a memset dispatch).
// ---------------------------------------------------------------------------
__global__ __launch_bounds__(256) void wprep_kernel(const float* __restrict__ w1,
                                                    const float* __restrict__ wn,
                                                    __bf16* __restrict__ wbuf,
                                                    float* __restrict__ g_acc)
{
    const int i = blockIdx.x * 256 + threadIdx.x;   // 0..65535
    if (blockIdx.x == 0 && threadIdx.x < 2 * N_EXP) g_acc[threadIdx.x] = 0.f;
    {
        const float v = w1[i];
        const __bf16 h = (__bf16)v;  const float r1 = v - (float)h;
        const __bf16 m = (__bf16)r1; const float r2 = r1 - (float)m;
        wbuf[i] = h; wbuf[WELEM + i] = m; wbuf[2 * WELEM + i] = (__bf16)r2;
    }
    {
        const float v = wn[i];
        const __bf16 h = (__bf16)v;  const float r1 = v - (float)h;
        const __bf16 m = (__bf16)r1; const float r2 = r1 - (float)m;
        wbuf[3 * WELEM + i] = h; wbuf[4 * WELEM + i] = m; wbuf[5 * WELEM + i] = (__bf16)r2;
    }
}

// Triple-split one 8-float x chunk into bf16 hi/mid/lo fragments.
__device__ __forceinline__ void split8(const float4 a, const float4 b,
                                       bf16x8& h, bf16x8& m, bf16x8& l)
{
    const float v[8] = {a.x, a.y, a.z, a.w, b.x, b.y, b.z, b.w};
    #pragma unroll
    for (int j = 0; j < 8; ++j) {
        const float vv = v[j];
        const __bf16 hh = (__bf16)vv;  const float r1 = vv - (float)hh;
        const __bf16 mm = (__bf16)r1;  const float r2 = r1 - (float)mm;
        h[j] = hh; m[j] = mm; l[j] = (__bf16)r2;
    }
}

// ---------------------------------------------------------------------------
// Fused gate kernel: block = 32 tokens, 8 waves, grid 512, 2 blocks/CU.
// THEORY (round 6): previous kernels touched each DRAM page of x 16 times,
// 128 B per touch (k split into 8 regions x 16 iters) -> activation-bound
// ~0.8-1 TB/s. Fix: K re-tiled into 16 windows of 256 floats; window c is
// staged as 32 tokens x 1 KB CONTIGUOUS runs (full-page consumption).
// Wave wv owns k-slices {c*256 + wv*32 .. +32} -- same work/instruction
// order per k-step as before, only the k->wave map changed (R0->R1 already
// proved such reorderings keep absmax bit-identical on this dataset).
// Staging dbuf: 2 x 8320 words = 66.5 KB, reused post-loop for reduction.
// ds_write: each wave writes 64 consecutive 16-B slots of one token row
// (conflict-free); ds_read_b128: quad-bank index (ml+2q) mod 8 uniform
// (conflict-free). T14 order per window: stage-loads -> weights -> ds_read
// -> split/MFMA -> ds_write -> barrier (1 barrier/window).
// A-frag: A[m=lane&15][k=(lane>>4)*8+j]; B-frag: B[k=(lane>>4)*8+j][n=lane&15];
// C/D: col(token)=lane&15, row(expert)=(lane>>4)*4+reg.   (HW-verified layouts)
// ---------------------------------------------------------------------------
__global__ __launch_bounds__(512, 4) void gate_kernel(
    const float* __restrict__ x, const __bf16* __restrict__ wbuf,
    const float* __restrict__ w2, const float* __restrict__ noise,
    float* __restrict__ out, float* __restrict__ g_imp, float* __restrict__ g_load)
{
    __shared__ float smem[2 * BUFW];     // staging dbuf; reused as red/dsum
    __shared__ float s_imp[N_EXP], s_ld[N_EXP];

    const int tid  = threadIdx.x;
    const int lane = tid & 63;
    const int wv   = tid >> 6;      // 0..7: k-sub-slice within each window
    const int ml   = lane & 15;     // A-row (expert) / B-col (token-in-tile)
    const int q    = lane >> 4;     // k-group
    const int t0   = blockIdx.x * (TILES * 16);

    const __bf16* w1h = wbuf;
    const __bf16* w1m = wbuf + WELEM;
    const __bf16* w1l = wbuf + 2 * WELEM;
    const __bf16* wnh = wbuf + 3 * WELEM;
    const __bf16* wnm = wbuf + 4 * WELEM;
    const __bf16* wnl = wbuf + 5 * WELEM;

    // weight base for this wave's k-sub-slice; + c*WINF per window
    const int wofc = ml * D_MODEL + wv * 32 + q * 8;

    // ---- staging map: fid = p*512+tid; token = fid>>6, slot = fid&63.
    //      Each wave loads one contiguous 1-KB token run per phase. ----
    int gi0, gi1, gi2, gi3, li0, li1, li2, li3;
    {
#define MAP(P, GI, LI)                                        \
        {   const int fid = (P) * 512 + tid;                  \
            const int tk  = fid >> 6;                         \
            const int sl  = fid & 63;                         \
            GI = (t0 + tk) * D_MODEL + sl * 4;                \
            LI = tk * TSTR + sl * 4;  }
        MAP(0, gi0, li0) MAP(1, gi1, li1) MAP(2, gi2, li2) MAP(3, gi3, li3)
#undef MAP
    }
    // consume offsets: lane reads token (tt*16+ml), words [wv*32+q*8 .. +8)
    const int lr0 = ml * TSTR + wv * 32 + q * 8;
    const int lr1 = (16 + ml) * TSTR + wv * 32 + q * 8;

    f32x4 c1[TILES], c2[TILES];
    #pragma unroll
    for (int tt = 0; tt < TILES; ++tt) {
        c1[tt] = (f32x4){0.f, 0.f, 0.f, 0.f};
        c2[tt] = (f32x4){0.f, 0.f, 0.f, 0.f};
    }

    float* bufA = smem;
    float* bufB = smem + BUFW;

    {   // prologue: stage window 0 into bufA
        const float4 s0 = *(const float4*)(x + gi0);
        const float4 s1 = *(const float4*)(x + gi1);
        const float4 s2 = *(const float4*)(x + gi2);
        const float4 s3 = *(const float4*)(x + gi3);
        *(float4*)(bufA + li0) = s0;
        *(float4*)(bufA + li1) = s1;
        *(float4*)(bufA + li2) = s2;
        *(float4*)(bufA + li3) = s3;
        __syncthreads();
    }

#define STEP(CUR, NXT, C)                                                     \
    {                                                                          \
        float4 sg0, sg1, sg2, sg3;                                             \
        if ((C) < NWIN - 1) {                                                  \
            const int co = ((C) + 1) * WINF;                                   \
            sg0 = *(const float4*)(x + gi0 + co);                              \
            sg1 = *(const float4*)(x + gi1 + co);                              \
            sg2 = *(const float4*)(x + gi2 + co);                              \
            sg3 = *(const float4*)(x + gi3 + co);                              \
        }                                                                      \
        const int wo = wofc + (C) * WINF;                                      \
        const bf16x8 a1h = *(const bf16x8*)(w1h + wo);                         \
        const bf16x8 a1m = *(const bf16x8*)(w1m + wo);                         \
        const bf16x8 a1l = *(const bf16x8*)(w1l + wo);                         \
        const bf16x8 a2h = *(const bf16x8*)(wnh + wo);                         \
        const bf16x8 a2m = *(const bf16x8*)(wnm + wo);                         \
        const bf16x8 a2l = *(const bf16x8*)(wnl + wo);                         \
        const float4 xa0 = *(const float4*)((CUR) + lr0);                      \
        const float4 xb0 = *(const float4*)((CUR) + lr0 + 4);                  \
        const float4 xa1 = *(const float4*)((CUR) + lr1);                      \
        const float4 xb1 = *(const float4*)((CUR) + lr1 + 4);                  \
        bf16x8 xh0, xm0, xl0, xh1, xm1, xl1;                                   \
        split8(xa0, xb0, xh0, xm0, xl0);                                       \
        split8(xa1, xb1, xh1, xm1, xl1);                                       \
        c1[0] = MFMA(a1h, xh0, c1[0]);  c2[0] = MFMA(a2h, xh0, c2[0]);         \
        c1[1] = MFMA(a1h, xh1, c1[1]);  c2[1] = MFMA(a2h, xh1, c2[1]);         \
        c1[0] = MFMA(a1h, xm0, c1[0]);  c2[0] = MFMA(a2h, xm0, c2[0]);         \
        c1[1] = MFMA(a1h, xm1, c1[1]);  c2[1] = MFMA(a2h, xm1, c2[1]);         \
        c1[0] = MFMA(a1m, xh0, c1[0]);  c2[0] = MFMA(a2m, xh0, c2[0]);         \
        c1[1] = MFMA(a1m, xh1, c1[1]);  c2[1] = MFMA(a2m, xh1, c2[1]);         \
        c1[0] = MFMA(a1h, xl0, c1[0]);  c2[0] = MFMA(a2h, xl0, c2[0]);         \
        c1[1] = MFMA(a1h, xl1, c1[1]);  c2[1] = MFMA(a2h, xl1, c2[1]);         \
        c1[0] = MFMA(a1l, xh0, c1[0]);  c2[0] = MFMA(a2l, xh0, c2[0]);         \
        c1[1] = MFMA(a1l, xh1, c1[1]);  c2[1] = MFMA(a2l, xh1, c2[1]);         \
        c1[0] = MFMA(a1m, xm0, c1[0]);  c2[0] = MFMA(a2m, xm0, c2[0]);         \
        c1[1] = MFMA(a1m, xm1, c1[1]);  c2[1] = MFMA(a2m, xm1, c2[1]);         \
        if ((C) < NWIN - 1) {                                                  \
            *(float4*)((NXT) + li0) = sg0;                                     \
            *(float4*)((NXT) + li1) = sg1;                                     \
            *(float4*)((NXT) + li2) = sg2;                                     \
            *(float4*)((NXT) + li3) = sg3;                                     \
        }                                                                      \
        __syncthreads();                                                       \
    }

    #pragma unroll
    for (int h = 0; h < NWIN / 2; ++h) {
        STEP(bufA, bufB, 2 * h)
        STEP(bufB, bufA, 2 * h + 1)
    }
#undef STEP

    // ---- reuse staging LDS: red = smem[0..8448), dsum = smem[8448..9504)
    float* red  = smem;
    float* dsum = smem + 8448;

    #pragma unroll
    for (int tt = 0; tt < TILES; ++tt) {
        #pragma unroll
        for (int r = 0; r < 4; ++r) {
            red[((wv * TILES + tt) * 16 + ml) * 33 + q * 4 + r]      = c1[tt][r];
            red[((wv * TILES + tt) * 16 + ml) * 33 + 16 + q * 4 + r] = c2[tt][r];
        }
    }
    __syncthreads();

    // 1024 partial-sum slots, 512 threads: two 8-way reductions each.
    for (int idx = tid; idx < TILES * 512; idx += 512) {
        const int tt = idx >> 9, tk = (idx >> 5) & 15, o = idx & 31;
        float s = 0.f;
        #pragma unroll
        for (int w = 0; w < 8; ++w) s += red[((w * TILES + tt) * 16 + tk) * 33 + o];
        dsum[(tt * 16 + tk) * 33 + o] = s;
    }
    if (tid < N_EXP) { s_imp[tid] = 0.f; s_ld[tid] = 0.f; }
    __syncthreads();

    // ---- per-token epilogue on 32 lanes ----
    if (tid < TILES * 16) {
        const int tt = tid >> 4, tk = tid & 15;
        const int t = t0 + tid;
        float dot[32];
        #pragma unroll
        for (int e = 0; e < 32; ++e) dot[e] = dsum[(tt * 16 + tk) * 33 + e];

        float th[N_EXP], nc[N_EXP];
        #pragma unroll
        for (int e = 0; e < N_EXP; ++e) th[e] = tanhf(dot[e]);
        #pragma unroll
        for (int e = 0; e < N_EXP; ++e) {
            const float v = dot[N_EXP + e];
            nc[e] = fmaxf(v, 0.f) + log1pf(expf(-fabsf(v))) + 0.01f;
        }

        float lg[N_EXP];
        #pragma unroll
        for (int f = 0; f < N_EXP; ++f) {
            float s = 0.f;
            #pragma unroll
            for (int e = 0; e < N_EXP; ++e) s = fmaf(th[e], w2[f * 16 + e], s);
            lg[f] = s;
        }

        float ln[N_EXP], v[N_EXP];
        {
            const float4* nz = (const float4*)(noise + (size_t)t * 16);
            const float4 n0 = nz[0], n1 = nz[1], n2 = nz[2], n3 = nz[3];
            const float nzv[16] = {n0.x, n0.y, n0.z, n0.w, n1.x, n1.y, n1.z, n1.w,
                                   n2.x, n2.y, n2.z, n2.w, n3.x, n3.y, n3.z, n3.w};
            #pragma unroll
            for (int e = 0; e < N_EXP; ++e) {
                ln[e] = nzv[e] * nc[e];
                v[e]  = lg[e] + ln[e];
            }
        }

        // top-5 selection (ties -> lowest index, matching lax.top_k)
        float tv[5]; int ti[5];
        #pragma unroll
        for (int j = 0; j < 5; ++j) {
            float best = -INFINITY; int bi = 0;
            #pragma unroll
            for (int e = 0; e < N_EXP; ++e) {
                bool taken = false;
                #pragma unroll
                for (int jj = 0; jj < 5; ++jj)
                    if (jj < j) taken = taken || (ti[jj] == e);
                if (!taken && v[e] > best) { best = v[e]; bi = e; }
            }
            tv[j] = best; ti[j] = bi;
        }

        const float mx = tv[0];
        float ex[4], ssum = 0.f;
        #pragma unroll
        for (int j = 0; j < 4; ++j) { ex[j] = expf(tv[j] - mx); ssum += ex[j]; }
        const float inv = 1.f / ssum;
        float sc[4];
        #pragma unroll
        for (int j = 0; j < 4; ++j) sc[j] = ex[j] * inv;

        #pragma unroll
        for (int j = 0; j < 4; ++j) atomicAdd(&s_imp[ti[j]], sc[j]);

        const float thr_in = tv[4], thr_out = tv[3];
        #pragma unroll
        for (int e = 0; e < N_EXP; ++e) {
            const bool  is_in = ln[e] > thr_in;
            const float thr   = is_in ? thr_in : thr_out;
            const float z     = (lg[e] - thr) / nc[e];
            const float prob  = 0.5f * (1.f + erff(z * 0.70710678118654752f));
            atomicAdd(&s_ld[e], prob);
        }

        ((float4*)out)[t] = make_float4((float)ti[0], (float)ti[1],
                                        (float)ti[2], (float)ti[3]);
        ((float4*)(out + N_TOK * N_SEL))[t] = make_float4(sc[0], sc[1], sc[2], sc[3]);
    }
    __syncthreads();
    if (tid < N_EXP)            atomicAdd(&g_imp[tid], s_imp[tid]);
    else if (tid < 2 * N_EXP)   atomicAdd(&g_load[tid - N_EXP], s_ld[tid - N_EXP]);
}

// ---------------------------------------------------------------------------
// gate loss = lambda * (cv2(importance) + cv2(load))
// ---------------------------------------------------------------------------
__global__ void loss_kernel(const float* __restrict__ g_imp,
                            const float* __restrict__ g_load,
                            float* __restrict__ out)
{
    if (threadIdx.x == 0 && blockIdx.x == 0) {
        double mi = 0.0, ml = 0.0;
        for (int e = 0; e < N_EXP; ++e) { mi += g_imp[e]; ml += g_load[e]; }
        mi /= N_EXP; ml /= N_EXP;
        double vi = 0.0, vl = 0.0;
        for (int e = 0; e < N_EXP; ++e) {
            const double di = g_imp[e] - mi;  vi += di * di;
            const double dl = g_load[e] - ml; vl += dl * dl;
        }
        vi /= (N_EXP - 1); vl /= (N_EXP - 1);
        const double ci = vi / (mi * mi + 1e-10);
        const double cl = vl / (ml * ml + 1e-10);
        out[N_TOK * N_SEL * 2] = (float)(0.01 * (ci + cl));
    }
}

// ---------------------------------------------------------------------------
extern "C" void kernel_launch(void* const* d_in, const int* in_sizes, int n_in,
                              void* d_out, int out_size, void* d_ws, size_t ws_size,
                              hipStream_t stream)
{
    const float* x     = (const float*)d_in[0];
    const float* w1    = (const float*)d_in[1];
    const float* w2    = (const float*)d_in[2];
    const float* wn    = (const float*)d_in[3];
    const float* noise = (const float*)d_in[4];
    float* out = (float*)d_out;

    __bf16* wbuf  = (__bf16*)d_ws;                              // 6*65536 bf16 = 768 KB
    float*  g_imp = (float*)((char*)d_ws + (1 << 20));          // 32 floats @ 1 MB
    float*  g_load = g_imp + N_EXP;

    wprep_kernel<<<WELEM / 256, 256, 0, stream>>>(w1, wn, wbuf, g_imp);
    gate_kernel<<<N_TOK / (TILES * 16), 512, 0, stream>>>(x, wbuf, w2, noise, out,
                                                          g_imp, g_load);
    loss_kernel<<<1, 64, 0, stream>>>(g_imp, g_load, out);
}